// Round 2
// baseline (2391.671 us; speedup 1.0000x reference)
//
#include <hip/hip_runtime.h>

// ---------------------------------------------------------------------------
// RatingLayer: 2-round fully-connected 2-node GRU + linear head.
//   h0 = features [4096, 4096] f32
//   per round: x = halfswap(h);  gi = x@W_ih^T+b_ih; gh = h@W_hh^T+b_hh; GRU.
//   out = h @ fc_w^T + fc_b  -> [4096, 1] f32
// Trick: x@W_ih^T == h@(W_ih P)^T, P = column half-swap. So stack
// [W_ih*P ; W_hh] -> one [24576,4096] bf16 B^T-layout GEMM per round.
// ---------------------------------------------------------------------------

typedef __bf16 bf16x8 __attribute__((ext_vector_type(8)));
typedef float  f32x4  __attribute__((ext_vector_type(4)));
typedef unsigned short u16x4 __attribute__((ext_vector_type(4)));

#define HH    4096        // H
#define NI_D  2048
#define N3H   12288
#define N6H   24576
#define BSZ   4096
#define BM    128
#define BN    128
#define BK    32
#define NBLK  (N6H / BN)              // 192
#define GRID_GEMM ((BSZ / BM) * NBLK) // 6144

__device__ __forceinline__ unsigned short f2bf(float f) {
  unsigned u = __float_as_uint(f);
  u += 0x7FFFu + ((u >> 16) & 1u);          // round-to-nearest-even
  return (unsigned short)(u >> 16);
}
__device__ __forceinline__ float bf2f(unsigned short s) {
  return __uint_as_float(((unsigned)s) << 16);
}

__device__ __forceinline__ void gload16(const void* g, void* l) {
  void* gv = (void*)g;  // strip const
  __builtin_amdgcn_global_load_lds(
      (__attribute__((address_space(1))) unsigned int*)gv,
      (__attribute__((address_space(3))) unsigned int*)l,
      16, 0, 0);
}

// --- W_comb[j][k]: j<3H -> bf16(W_ih[j][(k+NI)%H]) ; else bf16(W_hh[j-3H][k])
__global__ void __launch_bounds__(256)
convert_weights(const float* __restrict__ Wih, const float* __restrict__ Whh,
                unsigned short* __restrict__ Wc)
{
  int idx = (blockIdx.x * 256 + threadIdx.x) << 2;   // element in Wc
  int j = idx >> 12;          // /4096
  int k = idx & 4095;
  const float* src;
  if (j < N3H) src = Wih + (size_t)j * HH + ((k + NI_D) & (HH - 1));
  else         src = Whh + (size_t)(j - N3H) * HH + k;
  f32x4 v = *(const f32x4*)src;
  u16x4 o = { f2bf(v[0]), f2bf(v[1]), f2bf(v[2]), f2bf(v[3]) };
  *(u16x4*)(Wc + idx) = o;
}

__global__ void __launch_bounds__(256)
cast_f32_bf16(const float* __restrict__ src, unsigned short* __restrict__ dst)
{
  int i = (blockIdx.x * 256 + threadIdx.x) << 2;
  f32x4 v = *(const f32x4*)(src + i);
  u16x4 o = { f2bf(v[0]), f2bf(v[1]), f2bf(v[2]), f2bf(v[3]) };
  *(u16x4*)(dst + i) = o;
}

// --- C[M=4096, N=24576] bf16 = A[4096,4096] * B[24576,4096]^T  (all bf16)
// m97 structure: 128x128 tile, BK=32, 4 waves (2x2), 16x16x32 MFMA,
// global_load_lds width 16, 2 barriers per K-step, XCD-swizzled bid.
__global__ void __launch_bounds__(256)
gemm_bt(const unsigned short* __restrict__ A,
        const unsigned short* __restrict__ B,
        unsigned short* __restrict__ C)
{
  __shared__ alignas(16) unsigned short As[BM * BK];
  __shared__ alignas(16) unsigned short Bs[BN * BK];

  int bid = blockIdx.x;
  int wg  = (bid & 7) * (GRID_GEMM / 8) + (bid >> 3);  // bijective: 6144 % 8 == 0
  int m0  = (wg / NBLK) * BM;
  int n0  = (wg % NBLK) * BN;

  int t = threadIdx.x;
  int w = t >> 6;           // wave 0..3
  int l = t & 63;
  int wr = w >> 1, wc = w & 1;

  // staging: thread t covers tile row (p*64 + t/4), k-chunk (t%4)*8
  int srow = t >> 2;
  int scol = (t & 3) << 3;
  const unsigned short* Ag = A + (size_t)(m0 + srow) * HH + scol;
  const unsigned short* Bg = B + (size_t)(n0 + srow) * HH + scol;
  char* AsB = (char*)As + (size_t)w * 1024;   // wave-uniform LDS dest base
  char* BsB = (char*)Bs + (size_t)w * 1024;

  int lrow = l & 15;
  int lk   = (l >> 4) << 3;
  const unsigned short* aptr = &As[(wr * 64 + lrow) * BK + lk];
  const unsigned short* bptr = &Bs[(wc * 64 + lrow) * BK + lk];

  f32x4 acc[4][4] = {};

  for (int k0 = 0; k0 < HH; k0 += BK) {
    __syncthreads();                    // LDS free (prev iter reads done)
    gload16(Ag,            AsB);
    gload16(Ag + 64 * HH,  AsB + 4096);
    gload16(Bg,            BsB);
    gload16(Bg + 64 * HH,  BsB + 4096);
    Ag += BK; Bg += BK;
    __syncthreads();                    // vmcnt(0) drain: tile visible
    bf16x8 af[4], bv[4];
#pragma unroll
    for (int m = 0; m < 4; ++m) af[m] = *(const bf16x8*)(aptr + m * 16 * BK);
#pragma unroll
    for (int n = 0; n < 4; ++n) bv[n] = *(const bf16x8*)(bptr + n * 16 * BK);
#pragma unroll
    for (int m = 0; m < 4; ++m)
#pragma unroll
      for (int n = 0; n < 4; ++n)
        acc[m][n] = __builtin_amdgcn_mfma_f32_16x16x32_bf16(af[m], bv[n],
                                                            acc[m][n], 0, 0, 0);
  }

  // C/D layout (verified m89): col = lane&15, row = (lane>>4)*4 + reg
  int crow = m0 + wr * 64 + ((l >> 4) << 2);
  int ccol = n0 + wc * 64 + lrow;
#pragma unroll
  for (int m = 0; m < 4; ++m)
#pragma unroll
    for (int n = 0; n < 4; ++n)
#pragma unroll
      for (int i = 0; i < 4; ++i)
        C[(size_t)(crow + m * 16 + i) * N6H + (ccol + n * 16)] = f2bf(acc[m][n][i]);
}

// --- GRU pointwise. C rows: [gi_r gi_z gi_n gh_r gh_z gh_n] each HH wide.
// Writes h_new (f32) and h_new (bf16, next GEMM's A).
__global__ void __launch_bounds__(256)
gru_update(const unsigned short* __restrict__ C, const float* __restrict__ h_old,
           const float* __restrict__ b_ih, const float* __restrict__ b_hh,
           float* __restrict__ h_new, unsigned short* __restrict__ h_bf)
{
  int idx = blockIdx.x * 256 + threadIdx.x;   // 4096*1024 threads, 4 elems each
  int b = idx >> 10;
  int j = (idx & 1023) << 2;
  const unsigned short* Cr = C + (size_t)b * N6H;
  u16x4 gir = *(const u16x4*)(Cr + j);
  u16x4 giz = *(const u16x4*)(Cr + HH + j);
  u16x4 gin = *(const u16x4*)(Cr + 2 * HH + j);
  u16x4 ghr = *(const u16x4*)(Cr + 3 * HH + j);
  u16x4 ghz = *(const u16x4*)(Cr + 4 * HH + j);
  u16x4 ghn = *(const u16x4*)(Cr + 5 * HH + j);
  f32x4 bir = *(const f32x4*)(b_ih + j);
  f32x4 biz = *(const f32x4*)(b_ih + HH + j);
  f32x4 bin = *(const f32x4*)(b_ih + 2 * HH + j);
  f32x4 bhr = *(const f32x4*)(b_hh + j);
  f32x4 bhz = *(const f32x4*)(b_hh + HH + j);
  f32x4 bhn = *(const f32x4*)(b_hh + 2 * HH + j);
  f32x4 ho  = *(const f32x4*)(h_old + (size_t)b * HH + j);
  f32x4 hv; u16x4 hb;
#pragma unroll
  for (int e = 0; e < 4; ++e) {
    float r = 1.f / (1.f + expf(-(bf2f(gir[e]) + bir[e] + bf2f(ghr[e]) + bhr[e])));
    float z = 1.f / (1.f + expf(-(bf2f(giz[e]) + biz[e] + bf2f(ghz[e]) + bhz[e])));
    float n = tanhf(bf2f(gin[e]) + bin[e] + r * (bf2f(ghn[e]) + bhn[e]));
    float h = (1.f - z) * n + z * ho[e];
    hv[e] = h; hb[e] = f2bf(h);
  }
  *(f32x4*)(h_new + (size_t)b * HH + j) = hv;
  *(u16x4*)(h_bf + (size_t)b * HH + j)  = hb;
}

// --- out[b] = dot(h[b,:], fc_w) + fc_b   (f32, one block per row)
__global__ void __launch_bounds__(256)
final_fc(const float* __restrict__ h, const float* __restrict__ fcw,
         const float* __restrict__ fcb, float* __restrict__ out)
{
  int b = blockIdx.x, t = threadIdx.x;
  const float* row = h + (size_t)b * HH;
  float s = 0.f;
#pragma unroll
  for (int i = 0; i < 4; ++i) {
    int v4 = t + i * 256;
    f32x4 hv = *(const f32x4*)(row + v4 * 4);
    f32x4 wv = *(const f32x4*)(fcw + v4 * 4);
    s += hv[0] * wv[0] + hv[1] * wv[1] + hv[2] * wv[2] + hv[3] * wv[3];
  }
#pragma unroll
  for (int off = 32; off > 0; off >>= 1) s += __shfl_down(s, off);
  __shared__ float red[4];
  if ((t & 63) == 0) red[t >> 6] = s;
  __syncthreads();
  if (t == 0) out[b] = red[0] + red[1] + red[2] + red[3] + fcb[0];
}

extern "C" void kernel_launch(void* const* d_in, const int* in_sizes, int n_in,
                              void* d_out, int out_size, void* d_ws, size_t ws_size,
                              hipStream_t stream)
{
  const float* feat = (const float*)d_in[0];   // [4096,2,2048] == [4096,4096]
  const float* Wih  = (const float*)d_in[1];   // [12288,4096]
  const float* bih  = (const float*)d_in[2];   // [12288]
  const float* Whh  = (const float*)d_in[3];   // [12288,4096]
  const float* bhh  = (const float*)d_in[4];   // [12288]
  const float* fcw  = (const float*)d_in[5];   // [4096]
  const float* fcb  = (const float*)d_in[6];   // [1]
  float* out = (float*)d_out;

  char* ws = (char*)d_ws;
  unsigned short* Wc   = (unsigned short*)ws;                    // 201326592 B
  unsigned short* Cbuf = (unsigned short*)(ws + 201326592);      // 201326592 B
  unsigned short* hb   = (unsigned short*)(ws + 402653184);      //  33554432 B
  float*          hf   = (float*)(ws + 436207616);               //  67108864 B
  // total: 503316480 B

  convert_weights<<<98304, 256, 0, stream>>>(Wih, Whh, Wc);
  cast_f32_bf16<<<16384, 256, 0, stream>>>(feat, hb);

  // round 1 (h_old = features)
  gemm_bt<<<GRID_GEMM, 256, 0, stream>>>(hb, Wc, Cbuf);
  gru_update<<<16384, 256, 0, stream>>>(Cbuf, feat, bih, bhh, hf, hb);

  // round 2 (h_old = hf, in-place)
  gemm_bt<<<GRID_GEMM, 256, 0, stream>>>(hb, Wc, Cbuf);
  gru_update<<<16384, 256, 0, stream>>>(Cbuf, hf, bih, bhh, hf, hb);

  final_fc<<<4096, 256, 0, stream>>>(hf, fcw, fcb, out);
}

// Round 3
// 1756.476 us; speedup vs baseline: 1.3616x; 1.3616x over previous
//
#include <hip/hip_runtime.h>

// ---------------------------------------------------------------------------
// RatingLayer: 2-round fully-connected 2-node GRU + linear head.
// One [24576,4096]^T bf16 GEMM per round (W_ih column-half-swapped + stacked
// with W_hh). Round 3: 256x256/BK=64/8-wave GEMM, T2 XOR-swizzled LDS,
// counted-vmcnt double-buffer pipeline (T3/T4), setprio (T5), n-major blocks.
// ---------------------------------------------------------------------------

typedef __bf16 bf16x8 __attribute__((ext_vector_type(8)));
typedef float  f32x4  __attribute__((ext_vector_type(4)));
typedef unsigned short u16x4 __attribute__((ext_vector_type(4)));

#define HH    4096
#define NI_D  2048
#define N3H   12288
#define N6H   24576
#define BSZ   4096
#define BM    256
#define BN    256
#define BK    64
#define MT    (BSZ / BM)     // 16
#define NT    (N6H / BN)     // 96
#define GRID_GEMM (MT * NT)  // 1536
#define NKT   (HH / BK)      // 64 K-tiles

__device__ __forceinline__ unsigned short f2bf(float f) {
  unsigned u = __float_as_uint(f);
  u += 0x7FFFu + ((u >> 16) & 1u);
  return (unsigned short)(u >> 16);
}
__device__ __forceinline__ float bf2f(unsigned short s) {
  return __uint_as_float(((unsigned)s) << 16);
}

__device__ __forceinline__ void gload16(const void* g, void* l) {
  void* gv = (void*)g;
  __builtin_amdgcn_global_load_lds(
      (__attribute__((address_space(1))) unsigned int*)gv,
      (__attribute__((address_space(3))) unsigned int*)l,
      16, 0, 0);
}

// --- weight convert: Wc[j][k] = bf16( j<3H ? W_ih[j][(k+NI)%H] : W_hh[j-3H][k] )
__global__ void __launch_bounds__(256)
convert_weights(const float* __restrict__ Wih, const float* __restrict__ Whh,
                unsigned short* __restrict__ Wc)
{
  int idx = (blockIdx.x * 256 + threadIdx.x) << 2;
  int j = idx >> 12;
  int k = idx & 4095;
  const float* src;
  if (j < N3H) src = Wih + (size_t)j * HH + ((k + NI_D) & (HH - 1));
  else         src = Whh + (size_t)(j - N3H) * HH + k;
  f32x4 v = *(const f32x4*)src;
  u16x4 o = { f2bf(v[0]), f2bf(v[1]), f2bf(v[2]), f2bf(v[3]) };
  *(u16x4*)(Wc + idx) = o;
}

__global__ void __launch_bounds__(256)
cast_f32_bf16(const float* __restrict__ src, unsigned short* __restrict__ dst)
{
  int i = (blockIdx.x * 256 + threadIdx.x) << 2;
  f32x4 v = *(const f32x4*)(src + i);
  u16x4 o = { f2bf(v[0]), f2bf(v[1]), f2bf(v[2]), f2bf(v[3]) };
  *(u16x4*)(dst + i) = o;
}

// ---------------------------------------------------------------------------
// C[4096, 24576] bf16 = A[4096,4096] * B[24576,4096]^T   (bf16 in, bf16 out)
// 256x256 tile, BK=64, 512 threads (8 waves, 2Mx4N), LDS 128 KB (2 dbuf).
// LDS store map (T2): stored_byte(row, cb) = row*128 + (cb ^ ((row&7)<<4)).
// global_load_lds writes linearly -> pre-swizzle the GLOBAL source (rule 21).
// Pipeline: at end of tile t, stage tile t+2 into buf[t&1] (that buffer's
// reads are provably done: barrier precedes). Entry of tile t waits
// vmcnt(8) = tile t+1's 8 loads/wave outstanding. Never vmcnt(0) in loop.
// ---------------------------------------------------------------------------
__global__ void __launch_bounds__(512, 2)
gemm_bt(const unsigned short* __restrict__ A,
        const unsigned short* __restrict__ B,
        unsigned short* __restrict__ C)
{
  __shared__ alignas(16) char ldsb[131072];  // A: 2x32KB @0, B: 2x32KB @65536

  int bid = blockIdx.x;
  int wg  = (bid & 7) * (GRID_GEMM / 8) + (bid >> 3);  // XCD swizzle (1536%8==0)
  int nt  = wg / MT;          // n-major: 16 consecutive wg share one W panel
  int mt  = wg % MT;
  int m0  = mt * BM;
  int n0  = nt * BN;

  int t  = threadIdx.x;
  int wv = t >> 6;            // wave 0..7
  int l  = t & 63;
  int wm = wv >> 2;           // 0..1 : 128 rows of C
  int wn = wv & 3;            // 0..3 : 64 cols of C

  // --- staging source (pre-swizzled): round r covers tile rows r*64+wv*8+(l>>3)
  int srow  = wv * 8 + (l >> 3);
  int lbyte = ((l & 7) ^ (l >> 3)) << 4;     // stored (l&7)*16 XOR row&7 = l>>3
  unsigned aoff4[4], boff4[4];
#pragma unroll
  for (int r = 0; r < 4; ++r) {
    aoff4[r] = (unsigned)(m0 + r * 64 + srow) * (HH * 2) + lbyte;
    boff4[r] = (unsigned)(n0 + r * 64 + srow) * (HH * 2) + lbyte;
  }
  const char* Ab = (const char*)A;
  const char* Bb = (const char*)B;

  // --- read-side swizzled column offsets (per-lane constants)
  int offk0 = (((l >> 4) * 16))      ^ ((l & 7) << 4);
  int offk1 = (((l >> 4) * 16) + 64) ^ ((l & 7) << 4);
  int arow_off = (wm * 128 + (l & 15)) * 128;
  int brow_off = (wn * 64  + (l & 15)) * 128;

  f32x4 acc[8][4] = {};

#define STAGE(buf, kt) do {                                                   \
    int kk_ = ((kt) < NKT) ? (kt) : 0;                                        \
    unsigned kb_ = (unsigned)kk_ * 128;                                       \
    _Pragma("unroll")                                                         \
    for (int r_ = 0; r_ < 4; ++r_) {                                          \
      gload16(Ab + (size_t)(aoff4[r_] + kb_),                                 \
              ldsb + (buf) * 32768 + r_ * 8192 + wv * 1024);                  \
      gload16(Bb + (size_t)(boff4[r_] + kb_),                                 \
              ldsb + 65536 + (buf) * 32768 + r_ * 8192 + wv * 1024);          \
    }                                                                         \
  } while (0)

#define TILE(buf, ktn) do {                                                   \
    asm volatile("s_waitcnt vmcnt(8)" ::: "memory");                          \
    __builtin_amdgcn_s_barrier();                                             \
    asm volatile("" ::: "memory");                                            \
    const char* LA_ = ldsb + (buf) * 32768 + arow_off;                        \
    const char* LB_ = ldsb + 65536 + (buf) * 32768 + brow_off;                \
    bf16x8 bfr[4][2];                                                         \
    _Pragma("unroll")                                                         \
    for (int nf_ = 0; nf_ < 4; ++nf_) {                                       \
      bfr[nf_][0] = *(const bf16x8*)(LB_ + nf_ * 2048 + offk0);               \
      bfr[nf_][1] = *(const bf16x8*)(LB_ + nf_ * 2048 + offk1);               \
    }                                                                         \
    _Pragma("unroll")                                                         \
    for (int qm_ = 0; qm_ < 2; ++qm_) {                                       \
      bf16x8 afr[4][2];                                                       \
      _Pragma("unroll")                                                       \
      for (int m_ = 0; m_ < 4; ++m_) {                                        \
        afr[m_][0] = *(const bf16x8*)(LA_ + (qm_ * 4 + m_) * 2048 + offk0);   \
        afr[m_][1] = *(const bf16x8*)(LA_ + (qm_ * 4 + m_) * 2048 + offk1);   \
      }                                                                       \
      __builtin_amdgcn_s_setprio(1);                                          \
      _Pragma("unroll")                                                       \
      for (int ks_ = 0; ks_ < 2; ++ks_)                                       \
        _Pragma("unroll")                                                     \
        for (int m_ = 0; m_ < 4; ++m_)                                        \
          _Pragma("unroll")                                                   \
          for (int nf_ = 0; nf_ < 4; ++nf_)                                   \
            acc[qm_ * 4 + m_][nf_] = __builtin_amdgcn_mfma_f32_16x16x32_bf16( \
                afr[m_][ks_], bfr[nf_][ks_], acc[qm_ * 4 + m_][nf_], 0, 0, 0);\
      __builtin_amdgcn_s_setprio(0);                                          \
    }                                                                         \
    asm volatile("" ::: "memory");                                            \
    __builtin_amdgcn_s_barrier();                                             \
    STAGE(buf, ktn);                                                          \
  } while (0)

  STAGE(0, 0);
  STAGE(1, 1);
#pragma unroll 1
  for (int tt = 0; tt < NKT; tt += 2) {
    TILE(0, tt + 2);
    TILE(1, tt + 3);
  }
  asm volatile("s_waitcnt vmcnt(0)" ::: "memory");  // drain before LDS dealloc

#undef TILE
#undef STAGE

  // C-write: frag layout col = lane&15, row = (lane>>4)*4 + reg (m89)
  int crow = m0 + wm * 128 + ((l >> 4) << 2);
  int ccol = n0 + wn * 64 + (l & 15);
#pragma unroll
  for (int mf = 0; mf < 8; ++mf)
#pragma unroll
    for (int nf = 0; nf < 4; ++nf)
#pragma unroll
      for (int i = 0; i < 4; ++i)
        C[(size_t)(crow + mf * 16 + i) * N6H + (ccol + nf * 16)] =
            f2bf(acc[mf][nf][i]);
}

// --- GRU pointwise: C rows [gi_r gi_z gi_n gh_r gh_z gh_n], each HH wide.
__global__ void __launch_bounds__(256)
gru_update(const unsigned short* __restrict__ C, const float* __restrict__ h_old,
           const float* __restrict__ b_ih, const float* __restrict__ b_hh,
           float* __restrict__ h_new, unsigned short* __restrict__ h_bf)
{
  int idx = blockIdx.x * 256 + threadIdx.x;
  int b = idx >> 10;
  int j = (idx & 1023) << 2;
  const unsigned short* Cr = C + (size_t)b * N6H;
  u16x4 gir = *(const u16x4*)(Cr + j);
  u16x4 giz = *(const u16x4*)(Cr + HH + j);
  u16x4 gin = *(const u16x4*)(Cr + 2 * HH + j);
  u16x4 ghr = *(const u16x4*)(Cr + 3 * HH + j);
  u16x4 ghz = *(const u16x4*)(Cr + 4 * HH + j);
  u16x4 ghn = *(const u16x4*)(Cr + 5 * HH + j);
  f32x4 bir = *(const f32x4*)(b_ih + j);
  f32x4 biz = *(const f32x4*)(b_ih + HH + j);
  f32x4 bin = *(const f32x4*)(b_ih + 2 * HH + j);
  f32x4 bhr = *(const f32x4*)(b_hh + j);
  f32x4 bhz = *(const f32x4*)(b_hh + HH + j);
  f32x4 bhn = *(const f32x4*)(b_hh + 2 * HH + j);
  f32x4 ho  = *(const f32x4*)(h_old + (size_t)b * HH + j);
  f32x4 hv; u16x4 hb;
#pragma unroll
  for (int e = 0; e < 4; ++e) {
    float r = 1.f / (1.f + expf(-(bf2f(gir[e]) + bir[e] + bf2f(ghr[e]) + bhr[e])));
    float z = 1.f / (1.f + expf(-(bf2f(giz[e]) + biz[e] + bf2f(ghz[e]) + bhz[e])));
    float n = tanhf(bf2f(gin[e]) + bin[e] + r * (bf2f(ghn[e]) + bhn[e]));
    float h = (1.f - z) * n + z * ho[e];
    hv[e] = h; hb[e] = f2bf(h);
  }
  *(f32x4*)(h_new + (size_t)b * HH + j) = hv;
  *(u16x4*)(h_bf + (size_t)b * HH + j)  = hb;
}

// --- out[b] = dot(h[b,:], fc_w) + fc_b
__global__ void __launch_bounds__(256)
final_fc(const float* __restrict__ h, const float* __restrict__ fcw,
         const float* __restrict__ fcb, float* __restrict__ out)
{
  int b = blockIdx.x, t = threadIdx.x;
  const float* row = h + (size_t)b * HH;
  float s = 0.f;
#pragma unroll
  for (int i = 0; i < 4; ++i) {
    int v4 = t + i * 256;
    f32x4 hv = *(const f32x4*)(row + v4 * 4);
    f32x4 wv = *(const f32x4*)(fcw + v4 * 4);
    s += hv[0] * wv[0] + hv[1] * wv[1] + hv[2] * wv[2] + hv[3] * wv[3];
  }
#pragma unroll
  for (int off = 32; off > 0; off >>= 1) s += __shfl_down(s, off);
  __shared__ float red[4];
  if ((t & 63) == 0) red[t >> 6] = s;
  __syncthreads();
  if (t == 0) out[b] = red[0] + red[1] + red[2] + red[3] + fcb[0];
}

extern "C" void kernel_launch(void* const* d_in, const int* in_sizes, int n_in,
                              void* d_out, int out_size, void* d_ws, size_t ws_size,
                              hipStream_t stream)
{
  const float* feat = (const float*)d_in[0];
  const float* Wih  = (const float*)d_in[1];
  const float* bih  = (const float*)d_in[2];
  const float* Whh  = (const float*)d_in[3];
  const float* bhh  = (const float*)d_in[4];
  const float* fcw  = (const float*)d_in[5];
  const float* fcb  = (const float*)d_in[6];
  float* out = (float*)d_out;

  char* ws = (char*)d_ws;
  unsigned short* Wc   = (unsigned short*)ws;                    // 201326592 B
  unsigned short* Cbuf = (unsigned short*)(ws + 201326592);      // 201326592 B
  unsigned short* hb   = (unsigned short*)(ws + 402653184);      //  33554432 B
  float*          hf   = (float*)(ws + 436207616);               //  67108864 B

  convert_weights<<<98304, 256, 0, stream>>>(Wih, Whh, Wc);
  cast_f32_bf16<<<16384, 256, 0, stream>>>(feat, hb);

  gemm_bt<<<GRID_GEMM, 512, 0, stream>>>(hb, Wc, Cbuf);
  gru_update<<<16384, 256, 0, stream>>>(Cbuf, feat, bih, bhh, hf, hb);

  gemm_bt<<<GRID_GEMM, 512, 0, stream>>>(hb, Wc, Cbuf);
  gru_update<<<16384, 256, 0, stream>>>(Cbuf, hf, bih, bhh, hf, hb);

  final_fc<<<4096, 256, 0, stream>>>(hf, fcw, fcb, out);
}

// Round 4
// 1570.392 us; speedup vs baseline: 1.5230x; 1.1185x over previous
//
#include <hip/hip_runtime.h>

// ---------------------------------------------------------------------------
// RatingLayer: 2-round fully-connected 2-node GRU + linear head.
// One [24576,4096]^T bf16 GEMM per round (W_ih column-half-swapped + stacked
// with W_hh). Round 4: full 8-phase schedule (T3+T4) on the 256x256/BK=64
// kernel: per-phase {ds_read || 2 global_load_lds -> bar -> lgkm0 ->
// setprio+16 MFMA -> bar}, vmcnt(6) once per K-tile, never 0 in loop.
// T2 XOR-swizzle retained (conflicts were 0 in round 3).
// ---------------------------------------------------------------------------

typedef __bf16 bf16x8 __attribute__((ext_vector_type(8)));
typedef float  f32x4  __attribute__((ext_vector_type(4)));
typedef unsigned short u16x4 __attribute__((ext_vector_type(4)));

#define HH    4096
#define NI_D  2048
#define N3H   12288
#define N6H   24576
#define BSZ   4096
#define BM    256
#define BN    256
#define BK    64
#define MT    (BSZ / BM)     // 16
#define NT    (N6H / BN)     // 96
#define GRID_GEMM (MT * NT)  // 1536
#define NKT   (HH / BK)      // 64 K-tiles

__device__ __forceinline__ unsigned short f2bf(float f) {
  unsigned u = __float_as_uint(f);
  u += 0x7FFFu + ((u >> 16) & 1u);
  return (unsigned short)(u >> 16);
}
__device__ __forceinline__ float bf2f(unsigned short s) {
  return __uint_as_float(((unsigned)s) << 16);
}

__device__ __forceinline__ void gload16(const void* g, void* l) {
  void* gv = (void*)g;
  __builtin_amdgcn_global_load_lds(
      (__attribute__((address_space(1))) unsigned int*)gv,
      (__attribute__((address_space(3))) unsigned int*)l,
      16, 0, 0);
}

// --- weight convert: Wc[j][k] = bf16( j<3H ? W_ih[j][(k+NI)%H] : W_hh[j-3H][k] )
__global__ void __launch_bounds__(256)
convert_weights(const float* __restrict__ Wih, const float* __restrict__ Whh,
                unsigned short* __restrict__ Wc)
{
  int idx = (blockIdx.x * 256 + threadIdx.x) << 2;
  int j = idx >> 12;
  int k = idx & 4095;
  const float* src;
  if (j < N3H) src = Wih + (size_t)j * HH + ((k + NI_D) & (HH - 1));
  else         src = Whh + (size_t)(j - N3H) * HH + k;
  f32x4 v = *(const f32x4*)src;
  u16x4 o = { f2bf(v[0]), f2bf(v[1]), f2bf(v[2]), f2bf(v[3]) };
  *(u16x4*)(Wc + idx) = o;
}

__global__ void __launch_bounds__(256)
cast_f32_bf16(const float* __restrict__ src, unsigned short* __restrict__ dst)
{
  int i = (blockIdx.x * 256 + threadIdx.x) << 2;
  f32x4 v = *(const f32x4*)(src + i);
  u16x4 o = { f2bf(v[0]), f2bf(v[1]), f2bf(v[2]), f2bf(v[3]) };
  *(u16x4*)(dst + i) = o;
}

// ---------------------------------------------------------------------------
// GEMM helpers
// ---------------------------------------------------------------------------
// LDS map: buf d: A at d*32768 (256 rows x 128 B), B at 65536 + d*32768.
// Granule g = 64 rows = one gload16 per thread (8 KB). Linear LDS dest;
// source column pre-swizzled by ((row&7)<<4) (rule 21 both-sides).
__device__ __forceinline__ void stageA(const char* a_base, char* lds, int ldst,
                                       int d, int kt, int g) {
  int kc = (kt < NKT) ? kt : 0;                 // dummy tail loads, race-safe
  gload16(a_base + (size_t)kc * 128 + (size_t)g * 524288,
          lds + d * 32768 + g * 8192 + ldst);
}
__device__ __forceinline__ void stageB(const char* b_base, char* lds, int ldst,
                                       int d, int kt, int g) {
  int kc = (kt < NKT) ? kt : 0;
  gload16(b_base + (size_t)kc * 128 + (size_t)g * 524288,
          lds + 65536 + d * 32768 + g * 8192 + ldst);
}

template <int MB>
__device__ __forceinline__ void mfma16(f32x4 (&acc)[8][4],
                                       const bf16x8 (&aA)[2], const bf16x8 (&aB)[2],
                                       const bf16x8 (&bfr)[4][2]) {
  __builtin_amdgcn_s_setprio(1);
#pragma unroll
  for (int ks = 0; ks < 2; ++ks)
#pragma unroll
    for (int nf = 0; nf < 4; ++nf) {
      acc[MB][nf]     = __builtin_amdgcn_mfma_f32_16x16x32_bf16(
                          aA[ks], bfr[nf][ks], acc[MB][nf], 0, 0, 0);
      acc[MB + 1][nf] = __builtin_amdgcn_mfma_f32_16x16x32_bf16(
                          aB[ks], bfr[nf][ks], acc[MB + 1][nf], 0, 0, 0);
    }
  __builtin_amdgcn_s_setprio(0);
}

#define BAR   __builtin_amdgcn_s_barrier()
#define LGKM0 do { asm volatile("s_waitcnt lgkmcnt(0)" ::: "memory");          \
                   __builtin_amdgcn_sched_barrier(0); } while (0)

// One K-tile block: 4 phases. Phase q computes m-frags {6-2q, 7-2q} (descending
// so A rows free up bottom-first for the staggered staging).
// Stage schedule (ledger- and race-verified):
//   ph0: A(t1) G0,G2 -> buf D^1   (that buffer fully consumed last block)
//   ph1: B(t2) G0,G1 -> buf D     (B(t) consumed in ph0, ph0-end barrier)
//   ph2: B(t2) G2,G3 -> buf D
//   ph3: A(t2) G1,G3 -> buf D     (A rows 64-127/192-255 consumed ph0-1)
// Block end: vmcnt(6) retires exactly through K-tile (t+1)'s 8 loads.
template <int D>
__device__ __forceinline__ void kblock(char* lds, const char* a_base,
                                       const char* b_base, int ldst,
                                       int aro, int bro, int offk0, int offk1,
                                       int t1, int t2, f32x4 (&acc)[8][4]) {
  const char* LA = lds + D * 32768 + aro;
  const char* LB = lds + 65536 + D * 32768 + bro;
  bf16x8 bfr[4][2];

  // ---- phase 0: all B (8 reads) + A frags 6,7 (4 reads); stage 2
  {
#pragma unroll
    for (int nf = 0; nf < 4; ++nf) {
      bfr[nf][0] = *(const bf16x8*)(LB + nf * 2048 + offk0);
      bfr[nf][1] = *(const bf16x8*)(LB + nf * 2048 + offk1);
    }
    bf16x8 aA[2], aB[2];
    aA[0] = *(const bf16x8*)(LA + 6 * 2048 + offk0);
    aA[1] = *(const bf16x8*)(LA + 6 * 2048 + offk1);
    aB[0] = *(const bf16x8*)(LA + 7 * 2048 + offk0);
    aB[1] = *(const bf16x8*)(LA + 7 * 2048 + offk1);
    stageA(a_base, lds, ldst, D ^ 1, t1, 0);
    stageA(a_base, lds, ldst, D ^ 1, t1, 2);
    asm volatile("s_waitcnt lgkmcnt(8)" ::: "memory");  // throttle (12 reads)
    BAR; LGKM0;
    mfma16<6>(acc, aA, aB, bfr);
    BAR;
  }
  // ---- phase 1: A frags 4,5; stage B(t2) G0,G1
  {
    bf16x8 aA[2], aB[2];
    aA[0] = *(const bf16x8*)(LA + 4 * 2048 + offk0);
    aA[1] = *(const bf16x8*)(LA + 4 * 2048 + offk1);
    aB[0] = *(const bf16x8*)(LA + 5 * 2048 + offk0);
    aB[1] = *(const bf16x8*)(LA + 5 * 2048 + offk1);
    stageB(b_base, lds, ldst, D, t2, 0);
    stageB(b_base, lds, ldst, D, t2, 1);
    BAR; LGKM0;
    mfma16<4>(acc, aA, aB, bfr);
    BAR;
  }
  // ---- phase 2: A frags 2,3; stage B(t2) G2,G3
  {
    bf16x8 aA[2], aB[2];
    aA[0] = *(const bf16x8*)(LA + 2 * 2048 + offk0);
    aA[1] = *(const bf16x8*)(LA + 2 * 2048 + offk1);
    aB[0] = *(const bf16x8*)(LA + 3 * 2048 + offk0);
    aB[1] = *(const bf16x8*)(LA + 3 * 2048 + offk1);
    stageB(b_base, lds, ldst, D, t2, 2);
    stageB(b_base, lds, ldst, D, t2, 3);
    BAR; LGKM0;
    mfma16<2>(acc, aA, aB, bfr);
    BAR;
  }
  // ---- phase 3: A frags 0,1; stage A(t2) G1,G3; vmcnt(6) gate for next tile
  {
    bf16x8 aA[2], aB[2];
    aA[0] = *(const bf16x8*)(LA + 0 * 2048 + offk0);
    aA[1] = *(const bf16x8*)(LA + 0 * 2048 + offk1);
    aB[0] = *(const bf16x8*)(LA + 1 * 2048 + offk0);
    aB[1] = *(const bf16x8*)(LA + 1 * 2048 + offk1);
    stageA(a_base, lds, ldst, D, t2, 1);
    stageA(a_base, lds, ldst, D, t2, 3);
    BAR; LGKM0;
    mfma16<0>(acc, aA, aB, bfr);
    asm volatile("s_waitcnt vmcnt(6)" ::: "memory");  // K-tile t+1 landed
    BAR;
  }
}

// ---------------------------------------------------------------------------
// C[4096, 24576] bf16 = A[4096,4096] * B[24576,4096]^T   (bf16 in, bf16 out)
// 256x256 tile, BK=64, 512 threads (8 waves, 2Mx4N), LDS 128 KB (2 dbuf).
// ---------------------------------------------------------------------------
__global__ void __launch_bounds__(512, 2)
gemm_bt(const unsigned short* __restrict__ A,
        const unsigned short* __restrict__ B,
        unsigned short* __restrict__ C)
{
  __shared__ alignas(16) char lds[131072];

  int bid = blockIdx.x;
  int wg  = (bid & 7) * (GRID_GEMM / 8) + (bid >> 3);  // XCD swizzle, 1536%8==0
  int nt  = wg / MT;          // n-major: 16 consecutive wg share one W panel
  int mt  = wg % MT;
  int m0  = mt * BM;
  int n0  = nt * BN;

  int t  = threadIdx.x;
  int wv = t >> 6;
  int l  = t & 63;
  int wm = wv >> 2;
  int wn = wv & 3;

  // staging addressing: thread covers row rloc of a 64-row granule,
  // 16B chunk (l&7), source column XOR-preswizzled.
  int rloc   = wv * 8 + (l >> 3);
  int sg_col = ((l & 7) ^ (l >> 3)) << 4;
  const char* a_base = (const char*)A + (size_t)(m0 + rloc) * 8192 + sg_col;
  const char* b_base = (const char*)B + (size_t)(n0 + rloc) * 8192 + sg_col;
  int ldst = wv * 1024;       // wave-uniform LDS dest offset within granule

  // read-side swizzled offsets
  int offk0 = (((l >> 4) << 4)) ^ ((l & 7) << 4);
  int offk1 = offk0 ^ 64;
  int aro = (wm * 128 + (l & 15)) * 128;
  int bro = (wn * 64  + (l & 15)) * 128;

  f32x4 acc[8][4] = {};

  // prologue: K0 complete (8 loads), then K1 partial in steady-state order
  // (B(1) G0-3, A(1) G1,G3 = 6 loads); vmcnt(6) -> K0 landed, 6 in flight.
#pragma unroll
  for (int g = 0; g < 4; ++g) stageA(a_base, lds, ldst, 0, 0, g);
#pragma unroll
  for (int g = 0; g < 4; ++g) stageB(b_base, lds, ldst, 0, 0, g);
#pragma unroll
  for (int g = 0; g < 4; ++g) stageB(b_base, lds, ldst, 1, 1, g);
  stageA(a_base, lds, ldst, 1, 1, 1);
  stageA(a_base, lds, ldst, 1, 1, 3);
  asm volatile("s_waitcnt vmcnt(6)" ::: "memory");
  BAR;

#pragma unroll 1
  for (int tt = 0; tt < NKT; tt += 2) {
    kblock<0>(lds, a_base, b_base, ldst, aro, bro, offk0, offk1,
              tt + 1, tt + 2, acc);
    kblock<1>(lds, a_base, b_base, ldst, aro, bro, offk0, offk1,
              tt + 2, tt + 3, acc);
  }
  asm volatile("s_waitcnt vmcnt(0)" ::: "memory");  // drain dummy tail loads

  // C-write: frag layout col = lane&15, row = (lane>>4)*4 + reg (m89)
  int crow = m0 + wm * 128 + ((l >> 4) << 2);
  int ccol = n0 + wn * 64 + (l & 15);
#pragma unroll
  for (int mf = 0; mf < 8; ++mf)
#pragma unroll
    for (int nf = 0; nf < 4; ++nf)
#pragma unroll
      for (int i = 0; i < 4; ++i)
        C[(size_t)(crow + mf * 16 + i) * N6H + (ccol + nf * 16)] =
            f2bf(acc[mf][nf][i]);
}

// --- GRU pointwise: C rows [gi_r gi_z gi_n gh_r gh_z gh_n], each HH wide.
__global__ void __launch_bounds__(256)
gru_update(const unsigned short* __restrict__ C, const float* __restrict__ h_old,
           const float* __restrict__ b_ih, const float* __restrict__ b_hh,
           float* __restrict__ h_new, unsigned short* __restrict__ h_bf)
{
  int idx = blockIdx.x * 256 + threadIdx.x;
  int b = idx >> 10;
  int j = (idx & 1023) << 2;
  const unsigned short* Cr = C + (size_t)b * N6H;
  u16x4 gir = *(const u16x4*)(Cr + j);
  u16x4 giz = *(const u16x4*)(Cr + HH + j);
  u16x4 gin = *(const u16x4*)(Cr + 2 * HH + j);
  u16x4 ghr = *(const u16x4*)(Cr + 3 * HH + j);
  u16x4 ghz = *(const u16x4*)(Cr + 4 * HH + j);
  u16x4 ghn = *(const u16x4*)(Cr + 5 * HH + j);
  f32x4 bir = *(const f32x4*)(b_ih + j);
  f32x4 biz = *(const f32x4*)(b_ih + HH + j);
  f32x4 bin = *(const f32x4*)(b_ih + 2 * HH + j);
  f32x4 bhr = *(const f32x4*)(b_hh + j);
  f32x4 bhz = *(const f32x4*)(b_hh + HH + j);
  f32x4 bhn = *(const f32x4*)(b_hh + 2 * HH + j);
  f32x4 ho  = *(const f32x4*)(h_old + (size_t)b * HH + j);
  f32x4 hv; u16x4 hb;
#pragma unroll
  for (int e = 0; e < 4; ++e) {
    float r = 1.f / (1.f + expf(-(bf2f(gir[e]) + bir[e] + bf2f(ghr[e]) + bhr[e])));
    float z = 1.f / (1.f + expf(-(bf2f(giz[e]) + biz[e] + bf2f(ghz[e]) + bhz[e])));
    float n = tanhf(bf2f(gin[e]) + bin[e] + r * (bf2f(ghn[e]) + bhn[e]));
    float h = (1.f - z) * n + z * ho[e];
    hv[e] = h; hb[e] = f2bf(h);
  }
  *(f32x4*)(h_new + (size_t)b * HH + j) = hv;
  *(u16x4*)(h_bf + (size_t)b * HH + j)  = hb;
}

// --- out[b] = dot(h[b,:], fc_w) + fc_b
__global__ void __launch_bounds__(256)
final_fc(const float* __restrict__ h, const float* __restrict__ fcw,
         const float* __restrict__ fcb, float* __restrict__ out)
{
  int b = blockIdx.x, t = threadIdx.x;
  const float* row = h + (size_t)b * HH;
  float s = 0.f;
#pragma unroll
  for (int i = 0; i < 4; ++i) {
    int v4 = t + i * 256;
    f32x4 hv = *(const f32x4*)(row + v4 * 4);
    f32x4 wv = *(const f32x4*)(fcw + v4 * 4);
    s += hv[0] * wv[0] + hv[1] * wv[1] + hv[2] * wv[2] + hv[3] * wv[3];
  }
#pragma unroll
  for (int off = 32; off > 0; off >>= 1) s += __shfl_down(s, off);
  __shared__ float red[4];
  if ((t & 63) == 0) red[t >> 6] = s;
  __syncthreads();
  if (t == 0) out[b] = red[0] + red[1] + red[2] + red[3] + fcb[0];
}

extern "C" void kernel_launch(void* const* d_in, const int* in_sizes, int n_in,
                              void* d_out, int out_size, void* d_ws, size_t ws_size,
                              hipStream_t stream)
{
  const float* feat = (const float*)d_in[0];
  const float* Wih  = (const float*)d_in[1];
  const float* bih  = (const float*)d_in[2];
  const float* Whh  = (const float*)d_in[3];
  const float* bhh  = (const float*)d_in[4];
  const float* fcw  = (const float*)d_in[5];
  const float* fcb  = (const float*)d_in[6];
  float* out = (float*)d_out;

  char* ws = (char*)d_ws;
  unsigned short* Wc   = (unsigned short*)ws;                    // 201326592 B
  unsigned short* Cbuf = (unsigned short*)(ws + 201326592);      // 201326592 B
  unsigned short* hb   = (unsigned short*)(ws + 402653184);      //  33554432 B
  float*          hf   = (float*)(ws + 436207616);               //  67108864 B

  convert_weights<<<98304, 256, 0, stream>>>(Wih, Whh, Wc);
  cast_f32_bf16<<<16384, 256, 0, stream>>>(feat, hb);

  gemm_bt<<<GRID_GEMM, 512, 0, stream>>>(hb, Wc, Cbuf);
  gru_update<<<16384, 256, 0, stream>>>(Cbuf, feat, bih, bhh, hf, hb);

  gemm_bt<<<GRID_GEMM, 512, 0, stream>>>(hb, Wc, Cbuf);
  gru_update<<<16384, 256, 0, stream>>>(Cbuf, hf, bih, bhh, hf, hb);

  final_fc<<<4096, 256, 0, stream>>>(hf, fcw, fcb, out);
}

// Round 5
// 1546.478 us; speedup vs baseline: 1.5465x; 1.0155x over previous
//
#include <hip/hip_runtime.h>

// ---------------------------------------------------------------------------
// RatingLayer: 2-round fully-connected 2-node GRU + linear head.
// One [24576,4096]^T bf16 GEMM per round (W_ih column-half-swapped + stacked
// with W_hh). Round 5: m201-faithful quadrant phases (full-K=64 per phase,
// ds_reads 12/4/8/0 with cross-phase reg reuse), same race-verified staging
// ledger + vmcnt(6) gate; side kernels fused (convert+cast; gru2+FC atomic).
// ---------------------------------------------------------------------------

typedef __bf16 bf16x8 __attribute__((ext_vector_type(8)));
typedef float  f32x4  __attribute__((ext_vector_type(4)));
typedef unsigned short u16x4 __attribute__((ext_vector_type(4)));

#define HH    4096
#define NI_D  2048
#define N3H   12288
#define N6H   24576
#define BSZ   4096
#define BM    256
#define BN    256
#define BK    64
#define MT    (BSZ / BM)     // 16
#define NT    (N6H / BN)     // 96
#define GRID_GEMM (MT * NT)  // 1536
#define NKT   (HH / BK)      // 64 K-tiles

#define NB_W  98304          // convert_weights blocks
#define NB_C  16384          // cast blocks

__device__ __forceinline__ unsigned short f2bf(float f) {
  unsigned u = __float_as_uint(f);
  u += 0x7FFFu + ((u >> 16) & 1u);
  return (unsigned short)(u >> 16);
}
__device__ __forceinline__ float bf2f(unsigned short s) {
  return __uint_as_float(((unsigned)s) << 16);
}

__device__ __forceinline__ void gload16(const void* g, void* l) {
  void* gv = (void*)g;
  __builtin_amdgcn_global_load_lds(
      (__attribute__((address_space(1))) unsigned int*)gv,
      (__attribute__((address_space(3))) unsigned int*)l,
      16, 0, 0);
}

// --- fused prep: Wc[j][k] = bf16(j<3H ? W_ih[j][(k+NI)%H] : W_hh[j-3H][k]);
//     hb = bf16(features)
__global__ void __launch_bounds__(256)
prep(const float* __restrict__ Wih, const float* __restrict__ Whh,
     const float* __restrict__ feat,
     unsigned short* __restrict__ Wc, unsigned short* __restrict__ hb)
{
  int bid = blockIdx.x;
  if (bid < NB_W) {
    int idx = (bid * 256 + threadIdx.x) << 2;
    int j = idx >> 12;
    int k = idx & 4095;
    const float* src;
    if (j < N3H) src = Wih + (size_t)j * HH + ((k + NI_D) & (HH - 1));
    else         src = Whh + (size_t)(j - N3H) * HH + k;
    f32x4 v = *(const f32x4*)src;
    u16x4 o = { f2bf(v[0]), f2bf(v[1]), f2bf(v[2]), f2bf(v[3]) };
    *(u16x4*)(Wc + idx) = o;
  } else {
    int i = ((bid - NB_W) * 256 + threadIdx.x) << 2;
    f32x4 v = *(const f32x4*)(feat + i);
    u16x4 o = { f2bf(v[0]), f2bf(v[1]), f2bf(v[2]), f2bf(v[3]) };
    *(u16x4*)(hb + i) = o;
  }
}

// ---------------------------------------------------------------------------
// GEMM helpers. LDS: buf d: A at d*32768 (256 rows x 128 B), B at 65536+d*32768.
// Granule g = 64 rows = one gload16 per thread (8 KB). Linear LDS dest; global
// source column pre-swizzled by ((row&7)<<4) (rule 21 both-sides).
// ---------------------------------------------------------------------------
__device__ __forceinline__ void stageA(const char* a_base, char* lds, int ldst,
                                       int d, int kt, int g) {
  int kc = (kt < NKT) ? kt : 0;                 // dummy tail loads, race-safe
  gload16(a_base + (size_t)kc * 128 + (size_t)g * 524288,
          lds + d * 32768 + g * 8192 + ldst);
}
__device__ __forceinline__ void stageB(const char* b_base, char* lds, int ldst,
                                       int d, int kt, int g) {
  int kc = (kt < NKT) ? kt : 0;
  gload16(b_base + (size_t)kc * 128 + (size_t)g * 524288,
          lds + 65536 + d * 32768 + g * 8192 + ldst);
}

// One C-quadrant over full K=64: 16 MFMAs into acc[MB..MB+3][NB..NB+1].
template <int MB, int NB>
__device__ __forceinline__ void mfmaQ(f32x4 (&acc)[8][4],
                                      const bf16x8 (&af)[4][2],
                                      const bf16x8 (&bf)[2][2]) {
  __builtin_amdgcn_s_setprio(1);
#pragma unroll
  for (int ks = 0; ks < 2; ++ks)
#pragma unroll
    for (int mf = 0; mf < 4; ++mf)
#pragma unroll
      for (int nf = 0; nf < 2; ++nf)
        acc[MB + mf][NB + nf] = __builtin_amdgcn_mfma_f32_16x16x32_bf16(
            af[mf][ks], bf[nf][ks], acc[MB + mf][NB + nf], 0, 0, 0);
  __builtin_amdgcn_s_setprio(0);
}

#define BAR   __builtin_amdgcn_s_barrier()
#define LGKM0 do { asm volatile("s_waitcnt lgkmcnt(0)" ::: "memory");          \
                   __builtin_amdgcn_sched_barrier(0); } while (0)

// One K-tile (4 quadrant phases). Frag geometry: A frags 4-7 = granules G1
// (wm=0) / G3 (wm=1); frags 0-3 = G0/G2. B(t) fully consumed after ph1.
// Stage ledger (race-verified): ph0: A(t1)G0,G2 -> D^1 (completes tile t1);
// ph1: A(t2)G1,G3 -> D; ph2: B(t2)G0,G1 -> D; ph3: B(t2)G2,G3 -> D.
// Per-wave issue order gives vmcnt(6) at tile end == A(t1) landed.
template <int D>
__device__ __forceinline__ void kblock(char* lds, const char* a_base,
                                       const char* b_base, int ldst,
                                       int aro, int bro, int offk0, int offk1,
                                       int t1, int t2, f32x4 (&acc)[8][4]) {
  const char* LA = lds + D * 32768 + aro;
  const char* LB = lds + 65536 + D * 32768 + bro;
  bf16x8 a47[4][2], a03[4][2], b01[2][2], b23[2][2];

  // ---- ph0: Q(m4-7, n0-1). 12 ds_reads; stage A(t1) G0,G2 -> D^1.
#pragma unroll
  for (int mf = 0; mf < 4; ++mf) {
    a47[mf][0] = *(const bf16x8*)(LA + (4 + mf) * 2048 + offk0);
    a47[mf][1] = *(const bf16x8*)(LA + (4 + mf) * 2048 + offk1);
  }
#pragma unroll
  for (int nf = 0; nf < 2; ++nf) {
    b01[nf][0] = *(const bf16x8*)(LB + nf * 2048 + offk0);
    b01[nf][1] = *(const bf16x8*)(LB + nf * 2048 + offk1);
  }
  stageA(a_base, lds, ldst, D ^ 1, t1, 0);
  stageA(a_base, lds, ldst, D ^ 1, t1, 2);
  asm volatile("s_waitcnt lgkmcnt(8)" ::: "memory");  // throttle (12 reads)
  BAR; LGKM0;
  mfmaQ<4, 0>(acc, a47, b01);
  BAR;

  // ---- ph1: Q(m4-7, n2-3). 4 ds_reads; stage A(t2) G1,G3 -> D.
#pragma unroll
  for (int nf = 0; nf < 2; ++nf) {
    b23[nf][0] = *(const bf16x8*)(LB + (2 + nf) * 2048 + offk0);
    b23[nf][1] = *(const bf16x8*)(LB + (2 + nf) * 2048 + offk1);
  }
  stageA(a_base, lds, ldst, D, t2, 1);
  stageA(a_base, lds, ldst, D, t2, 3);
  BAR; LGKM0;
  mfmaQ<4, 2>(acc, a47, b23);
  BAR;

  // ---- ph2: Q(m0-3, n0-1). 8 ds_reads; stage B(t2) G0,G1 -> D.
#pragma unroll
  for (int mf = 0; mf < 4; ++mf) {
    a03[mf][0] = *(const bf16x8*)(LA + mf * 2048 + offk0);
    a03[mf][1] = *(const bf16x8*)(LA + mf * 2048 + offk1);
  }
  stageB(b_base, lds, ldst, D, t2, 0);
  stageB(b_base, lds, ldst, D, t2, 1);
  BAR; LGKM0;
  mfmaQ<0, 0>(acc, a03, b01);
  BAR;

  // ---- ph3: Q(m0-3, n2-3). 0 ds_reads; stage B(t2) G2,G3 -> D; vmcnt gate.
  stageB(b_base, lds, ldst, D, t2, 2);
  stageB(b_base, lds, ldst, D, t2, 3);
  BAR;
  mfmaQ<0, 2>(acc, a03, b23);
  asm volatile("s_waitcnt vmcnt(6)" ::: "memory");    // tile t1 landed
  BAR;
}

// ---------------------------------------------------------------------------
// C[4096, 24576] bf16 = A[4096,4096] * B[24576,4096]^T   (bf16 in, bf16 out)
// 256x256 tile, BK=64, 512 threads (8 waves, 2Mx4N), LDS 128 KB (2 dbuf).
// ---------------------------------------------------------------------------
__global__ void __launch_bounds__(512, 2)
gemm_bt(const unsigned short* __restrict__ A,
        const unsigned short* __restrict__ B,
        unsigned short* __restrict__ C)
{
  __shared__ alignas(16) char lds[131072];

  int bid = blockIdx.x;
  int wg  = (bid & 7) * (GRID_GEMM / 8) + (bid >> 3);  // XCD swizzle, 1536%8==0
  int nt  = wg / MT;          // n-major: 16 consecutive wg share one W panel
  int mt  = wg % MT;
  int m0  = mt * BM;
  int n0  = nt * BN;

  int t  = threadIdx.x;
  int wv = t >> 6;
  int l  = t & 63;
  int wm = wv >> 2;
  int wn = wv & 3;

  // staging: thread covers row rloc of a 64-row granule, 16B chunk (l&7),
  // source column XOR-preswizzled by row&7 = l>>3.
  int rloc   = wv * 8 + (l >> 3);
  int sg_col = ((l & 7) ^ (l >> 3)) << 4;
  const char* a_base = (const char*)A + (size_t)(m0 + rloc) * 8192 + sg_col;
  const char* b_base = (const char*)B + (size_t)(n0 + rloc) * 8192 + sg_col;
  int ldst = wv * 1024;       // wave-uniform LDS dest offset within granule

  // read-side swizzled offsets
  int offk0 = ((l >> 4) << 4) ^ ((l & 7) << 4);
  int offk1 = offk0 ^ 64;
  int aro = (wm * 128 + (l & 15)) * 128;
  int bro = (wn * 64  + (l & 15)) * 128;

  f32x4 acc[8][4] = {};

  // prologue: tile0 complete (8), then steady-state in-flight set for tile1:
  // A(1)G1,G3 + B(1)G0-3 = 6. vmcnt(6) -> tile0 landed, 6 outstanding.
#pragma unroll
  for (int g = 0; g < 4; ++g) stageA(a_base, lds, ldst, 0, 0, g);
#pragma unroll
  for (int g = 0; g < 4; ++g) stageB(b_base, lds, ldst, 0, 0, g);
  stageA(a_base, lds, ldst, 1, 1, 1);
  stageA(a_base, lds, ldst, 1, 1, 3);
#pragma unroll
  for (int g = 0; g < 4; ++g) stageB(b_base, lds, ldst, 1, 1, g);
  asm volatile("s_waitcnt vmcnt(6)" ::: "memory");
  BAR;

#pragma unroll 1
  for (int tt = 0; tt < NKT; tt += 2) {
    kblock<0>(lds, a_base, b_base, ldst, aro, bro, offk0, offk1,
              tt + 1, tt + 2, acc);
    kblock<1>(lds, a_base, b_base, ldst, aro, bro, offk0, offk1,
              tt + 2, tt + 3, acc);
  }
  asm volatile("s_waitcnt vmcnt(0)" ::: "memory");  // drain dummy tail loads

  // C-write: frag layout col = lane&15, row = (lane>>4)*4 + reg (m89)
  int crow = m0 + wm * 128 + ((l >> 4) << 2);
  int ccol = n0 + wn * 64 + (l & 15);
#pragma unroll
  for (int mf = 0; mf < 8; ++mf)
#pragma unroll
    for (int nf = 0; nf < 4; ++nf)
#pragma unroll
      for (int i = 0; i < 4; ++i)
        C[(size_t)(crow + mf * 16 + i) * N6H + (ccol + nf * 16)] =
            f2bf(acc[mf][nf][i]);
}

// --- round-1 GRU: h_old = features (f32); writes h1 as bf16 only.
__global__ void __launch_bounds__(256)
gru1(const unsigned short* __restrict__ C, const float* __restrict__ h_old,
     const float* __restrict__ b_ih, const float* __restrict__ b_hh,
     unsigned short* __restrict__ h_bf)
{
  int idx = blockIdx.x * 256 + threadIdx.x;
  int b = idx >> 10;
  int j = (idx & 1023) << 2;
  const unsigned short* Cr = C + (size_t)b * N6H;
  u16x4 gir = *(const u16x4*)(Cr + j);
  u16x4 giz = *(const u16x4*)(Cr + HH + j);
  u16x4 gin = *(const u16x4*)(Cr + 2 * HH + j);
  u16x4 ghr = *(const u16x4*)(Cr + 3 * HH + j);
  u16x4 ghz = *(const u16x4*)(Cr + 4 * HH + j);
  u16x4 ghn = *(const u16x4*)(Cr + 5 * HH + j);
  f32x4 bir = *(const f32x4*)(b_ih + j);
  f32x4 biz = *(const f32x4*)(b_ih + HH + j);
  f32x4 bin = *(const f32x4*)(b_ih + 2 * HH + j);
  f32x4 bhr = *(const f32x4*)(b_hh + j);
  f32x4 bhz = *(const f32x4*)(b_hh + HH + j);
  f32x4 bhn = *(const f32x4*)(b_hh + 2 * HH + j);
  f32x4 ho  = *(const f32x4*)(h_old + (size_t)b * HH + j);
  u16x4 hb;
#pragma unroll
  for (int e = 0; e < 4; ++e) {
    float r = 1.f / (1.f + expf(-(bf2f(gir[e]) + bir[e] + bf2f(ghr[e]) + bhr[e])));
    float z = 1.f / (1.f + expf(-(bf2f(giz[e]) + biz[e] + bf2f(ghz[e]) + bhz[e])));
    float n = tanhf(bf2f(gin[e]) + bin[e] + r * (bf2f(ghn[e]) + bhn[e]));
    hb[e] = f2bf((1.f - z) * n + z * ho[e]);
  }
  *(u16x4*)(h_bf + (size_t)b * HH + j) = hb;
}

// --- round-2 GRU fused with FC head: h_old = h1 (bf16); per-block partial
// dot(h2, fc_w) -> atomicAdd(out[b]). out zeroed by memset each call.
__global__ void __launch_bounds__(256)
gru2_fc(const unsigned short* __restrict__ C,
        const unsigned short* __restrict__ h_old_bf,
        const float* __restrict__ b_ih, const float* __restrict__ b_hh,
        const float* __restrict__ fcw, const float* __restrict__ fcb,
        float* __restrict__ out)
{
  int idx = blockIdx.x * 256 + threadIdx.x;
  int b = idx >> 10;
  int j = (idx & 1023) << 2;
  const unsigned short* Cr = C + (size_t)b * N6H;
  u16x4 gir = *(const u16x4*)(Cr + j);
  u16x4 giz = *(const u16x4*)(Cr + HH + j);
  u16x4 gin = *(const u16x4*)(Cr + 2 * HH + j);
  u16x4 ghr = *(const u16x4*)(Cr + 3 * HH + j);
  u16x4 ghz = *(const u16x4*)(Cr + 4 * HH + j);
  u16x4 ghn = *(const u16x4*)(Cr + 5 * HH + j);
  f32x4 bir = *(const f32x4*)(b_ih + j);
  f32x4 biz = *(const f32x4*)(b_ih + HH + j);
  f32x4 bin = *(const f32x4*)(b_ih + 2 * HH + j);
  f32x4 bhr = *(const f32x4*)(b_hh + j);
  f32x4 bhz = *(const f32x4*)(b_hh + HH + j);
  f32x4 bhn = *(const f32x4*)(b_hh + 2 * HH + j);
  u16x4 hob = *(const u16x4*)(h_old_bf + (size_t)b * HH + j);
  f32x4 fw  = *(const f32x4*)(fcw + j);
  float s = 0.f;
#pragma unroll
  for (int e = 0; e < 4; ++e) {
    float r = 1.f / (1.f + expf(-(bf2f(gir[e]) + bir[e] + bf2f(ghr[e]) + bhr[e])));
    float z = 1.f / (1.f + expf(-(bf2f(giz[e]) + biz[e] + bf2f(ghz[e]) + bhz[e])));
    float n = tanhf(bf2f(gin[e]) + bin[e] + r * (bf2f(ghn[e]) + bhn[e]));
    float h = (1.f - z) * n + z * bf2f(hob[e]);
    s += h * fw[e];
  }
#pragma unroll
  for (int off = 32; off > 0; off >>= 1) s += __shfl_down(s, off);
  __shared__ float red[4];
  if ((threadIdx.x & 63) == 0) red[threadIdx.x >> 6] = s;
  __syncthreads();
  if (threadIdx.x == 0) {
    float v = red[0] + red[1] + red[2] + red[3];
    if ((blockIdx.x & 3) == 0) v += fcb[0];
    atomicAdd(&out[b], v);
  }
}

extern "C" void kernel_launch(void* const* d_in, const int* in_sizes, int n_in,
                              void* d_out, int out_size, void* d_ws, size_t ws_size,
                              hipStream_t stream)
{
  const float* feat = (const float*)d_in[0];
  const float* Wih  = (const float*)d_in[1];
  const float* bih  = (const float*)d_in[2];
  const float* Whh  = (const float*)d_in[3];
  const float* bhh  = (const float*)d_in[4];
  const float* fcw  = (const float*)d_in[5];
  const float* fcb  = (const float*)d_in[6];
  float* out = (float*)d_out;

  char* ws = (char*)d_ws;
  unsigned short* Wc   = (unsigned short*)ws;                    // 201326592 B
  unsigned short* Cbuf = (unsigned short*)(ws + 201326592);      // 201326592 B
  unsigned short* hb   = (unsigned short*)(ws + 402653184);      //  33554432 B
  // total: 436207616 B

  hipMemsetAsync(out, 0, (size_t)out_size * sizeof(float), stream);
  prep<<<NB_W + NB_C, 256, 0, stream>>>(Wih, Whh, feat, Wc, hb);

  gemm_bt<<<GRID_GEMM, 512, 0, stream>>>(hb, Wc, Cbuf);
  gru1<<<16384, 256, 0, stream>>>(Cbuf, feat, bih, bhh, hb);

  gemm_bt<<<GRID_GEMM, 512, 0, stream>>>(hb, Wc, Cbuf);
  gru2_fc<<<16384, 256, 0, stream>>>(Cbuf, hb, bih, bhh, fcw, fcb, out);
}